// Round 1
// baseline (361.718 us; speedup 1.0000x reference)
//
#include <hip/hip_runtime.h>
#include <hip/hip_bf16.h>
#include <stdint.h>

#define HN 16
#define HH 224
#define HWD 224
#define HWP (HH*HWD)      // 50176
#define PH 112
#define PW 112
#define PHW (PH*PW)       // 12544
#define FCK 200704
#define KSEG 196

// ---------------- selector masks (depth-only, shared by both convs) ----------------
__global__ __launch_bounds__(256) void sel_kernel(
    const float* __restrict__ depth, const float* __restrict__ fxp,
    uint32_t* __restrict__ sel) {
  int idx = blockIdx.x*256 + threadIdx.x;           // 16*224*224 = 3136*256 exact
  int w = idx % HWD; int h = (idx / HWD) % HH; int n = idx / HWP;
  const float* dn = depth + n*HWP;
  float c = dn[h*HWD + w];
  float fx = fxp[0];
  float gr = c / fx;
  float half = gr * 0.5f;
  uint32_t bits = 0;
  #pragma unroll
  for (int i = 0; i < 3; ++i)
    #pragma unroll
    for (int j = 0; j < 3; ++j) {
      int y = h + i - 1, x = w + j - 1;
      float d = 0.0f;
      if (y >= 0 && y < HH && x >= 0 && x < HWD) d = dn[y*HWD + x];
      int k = i*3 + j;
      uint32_t b = 0;
      if (fabsf(d - (c + gr)) <= half) b |= 1u;   // m0 -> w0
      if (fabsf(d - c) < half)         b |= 2u;   // m1 -> w1 (strict <)
      if (fabsf(d - (c - gr)) <= half) b |= 4u;   // m2 -> w2
      bits |= b << (3*k);
    }
  sel[idx] = bits;
}

// ---------------- conv1: 3->16, thread per pixel, branchless jsel gather ----------------
__global__ __launch_bounds__(256) void conv1_kernel(
    const float* __restrict__ x, const uint32_t* __restrict__ sel,
    const float* __restrict__ w0, const float* __restrict__ w1,
    const float* __restrict__ w2, const float* __restrict__ bias,
    float* __restrict__ h1t) {
  __shared__ float wl[1728];   // layout t = k*192 + c*64 + o*4 + j  (j==3 slot = zeros)
  int tid = threadIdx.x;
  for (int t = tid; t < 1728; t += 256) {
    int j = t & 3; int o = (t >> 2) & 15; int c = (t >> 6) % 3; int k = t / 192;
    float v = 0.f;
    if (j == 0) v = w0[o*27 + c*9 + k];
    else if (j == 1) v = w1[o*27 + c*9 + k];
    else if (j == 2) v = w2[o*27 + c*9 + k];
    wl[t] = v;
  }
  __syncthreads();
  int idx = blockIdx.x*256 + tid;
  int w = idx % HWD; int h = (idx / HWD) % HH; int n = idx / HWP;
  uint32_t bits = sel[idx];
  const float* xn = x + n*3*HWP;
  float acc[16];
  #pragma unroll
  for (int o = 0; o < 16; ++o) acc[o] = 0.f;
  #pragma unroll
  for (int k = 0; k < 9; ++k) {
    uint32_t b = (bits >> (3*k)) & 7u;
    int jsel = (b & 1) ? 0 : (b & 2) ? 1 : (b & 4) ? 2 : 3;
    int y = h + k/3 - 1; int xx = w + (k%3) - 1;
    y = min(max(y,0), HH-1); xx = min(max(xx,0), HWD-1);   // clamped; zero-weight slot kills OOB
    const float* xp = xn + y*HWD + xx;
    #pragma unroll
    for (int c = 0; c < 3; ++c) {
      float xc = xp[c*HWP];
      const float* wp = &wl[(k*3 + c)*64 + jsel];
      #pragma unroll
      for (int o = 0; o < 16; ++o)
        acc[o] += wp[o*4] * xc;
    }
  }
  float4 s[4];
  #pragma unroll
  for (int o = 0; o < 16; ++o)
    ((float*)s)[o] = fmaxf(acc[o] + bias[o], 0.f);
  float4* op = (float4*)(h1t + (size_t)idx*16);    // channel-last [n][h][w][16]
  op[0]=s[0]; op[1]=s[1]; op[2]=s[2]; op[3]=s[3];
}

// ---------------- conv2: 16->16 + ReLU + 2x2 maxpool, wave per pooled pixel ----------------
// lane = (cgrp, o); weights in VGPR (3*9*4 = 108/lane); selector wave-uniform -> scalar branches
__global__ __launch_bounds__(256) void conv2_kernel(
    const float* __restrict__ h1t, const uint32_t* __restrict__ sel,
    const float* __restrict__ w0, const float* __restrict__ w1,
    const float* __restrict__ w2, const float* __restrict__ bias,
    float* __restrict__ outcf) {
  __shared__ __align__(16) float xs[18*18*16];   // staged h1 tile, [y][x][c], channel-last
  __shared__ float pl[64*17];                    // pooled tile [pix][o], padded
  int tid = threadIdx.x;
  int b = blockIdx.x;                            // 16n * 196 tiles
  int n = b / 196; int rem = b % 196;
  int br = rem / 14; int bc = rem % 14;
  int y0 = br*16 - 1;
  int x0 = bc*16 - 1;
  for (int t = tid; t < 18*18*16; t += 256) {
    int c = t & 15; int gx_ = (t >> 4) % 18; int gy_ = t / 288;
    int gy = min(max(y0 + gy_, 0), HH-1);
    int gx = min(max(x0 + gx_, 0), HWD-1);
    xs[t] = h1t[((size_t)(n*HWP + gy*HWD + gx))*16 + c];
  }
  int lane = tid & 63;
  int o = lane & 15, cgrp = lane >> 4;
  float wreg[3][9][4];
  {
    const float* ws0[3] = {w0, w1, w2};
    #pragma unroll
    for (int j = 0; j < 3; ++j) {
      const float* wp = ws0[j] + o*144 + cgrp*36;
      #pragma unroll
      for (int cc = 0; cc < 4; ++cc)
        #pragma unroll
        for (int k = 0; k < 9; ++k)
          wreg[j][k][cc] = wp[cc*9 + k];
    }
  }
  float bo = bias[o];
  __syncthreads();
  int wid = __builtin_amdgcn_readfirstlane(tid >> 6);
  const uint32_t* sn = sel + n*HWP;
  for (int pp = 0; pp < 16; ++pp) {
    int pr = wid*2 + (pp >> 3);
    int pc = pp & 7;
    float pool = 0.f;                            // post-ReLU values are >= 0
    #pragma unroll
    for (int dy = 0; dy < 2; ++dy)
      #pragma unroll
      for (int dx = 0; dx < 2; ++dx) {
        int cy = pr*2 + dy, cx = pc*2 + dx;      // 0..15 in tile
        int gy = br*16 + cy, gx = bc*16 + cx;
        uint32_t bits = sn[gy*HWD + gx];         // wave-uniform -> scalar
        float acc = 0.f;
        #pragma unroll
        for (int k = 0; k < 9; ++k) {
          uint32_t bb = (bits >> (3*k)) & 7u;
          if (!bb) continue;                     // uniform skip (~44% of taps)
          const float4 xv = *(const float4*)&xs[((cy + k/3)*18 + (cx + k%3))*16 + cgrp*4];
          if (bb & 1u) acc += wreg[0][k][0]*xv.x + wreg[0][k][1]*xv.y + wreg[0][k][2]*xv.z + wreg[0][k][3]*xv.w;
          if (bb & 2u) acc += wreg[1][k][0]*xv.x + wreg[1][k][1]*xv.y + wreg[1][k][2]*xv.z + wreg[1][k][3]*xv.w;
          if (bb & 4u) acc += wreg[2][k][0]*xv.x + wreg[2][k][1]*xv.y + wreg[2][k][2]*xv.z + wreg[2][k][3]*xv.w;
        }
        acc += __shfl_xor(acc, 16, 64);          // reduce over 4 c-groups
        acc += __shfl_xor(acc, 32, 64);
        float v = fmaxf(acc + bo, 0.f);
        pool = fmaxf(pool, v);
      }
    if (lane < 16) pl[(pr*8 + pc)*17 + o] = pool;
  }
  __syncthreads();
  for (int t = tid; t < 1024; t += 256) {        // repack to channel-first for FC1
    int oo = t >> 6; int pix = t & 63;
    int r = pix >> 3, col = pix & 7;
    outcf[(size_t)((n*16 + oo)*PH + br*8 + r)*PW + bc*8 + col] = pl[pix*17 + oo];
  }
}

// ---------------- FC1: C[16,128] = h[16,K] * W^T, split-K with LDS tiles ----------------
__global__ __launch_bounds__(256) void fc1_kernel(
    const float* __restrict__ hin, const float* __restrict__ wgt,
    float* __restrict__ partial) {
  __shared__ __align__(16) float hl[16*132];
  __shared__ __align__(16) float wl[16*132];
  int tid = threadIdx.x;
  int otile = blockIdx.x & 7;      // 8 tiles of 16 outputs
  int kseg  = blockIdx.x >> 3;     // 196 segments
  int obase = otile << 4;
  int nn = tid >> 4, oo = tid & 15;
  float acc = 0.f;
  int kb = kseg * (8*128);
  for (int ch = 0; ch < 8; ++ch, kb += 128) {
    __syncthreads();
    int r = tid >> 7; int f = tid & 127;
    #pragma unroll
    for (int rr = 0; rr < 8; ++rr) {
      int row = (rr << 1) | r;
      hl[row*132 + f] = hin[row*FCK + kb + f];
      wl[row*132 + f] = wgt[(size_t)(obase + row)*FCK + kb + f];
    }
    __syncthreads();
    const float4* hp = (const float4*)&hl[nn*132];
    const float4* wp = (const float4*)&wl[oo*132];
    #pragma unroll
    for (int q = 0; q < 32; ++q) {
      float4 a = hp[q], bq = wp[q];
      acc += a.x*bq.x + a.y*bq.y + a.z*bq.z + a.w*bq.w;
    }
  }
  partial[(size_t)(kseg*16 + nn)*128 + obase + oo] = acc;
}

__global__ __launch_bounds__(256) void fc1_reduce_kernel(
    const float* __restrict__ partial, const float* __restrict__ bias,
    float* __restrict__ outp) {
  int idx = blockIdx.x*256 + threadIdx.x;   // 2048
  int o = idx & 127;
  float s = bias[o];
  for (int k = 0; k < KSEG; ++k) s += partial[(size_t)k*2048 + idx];
  outp[idx] = s;
}

// ---------------- FC2 + log_softmax ----------------
__global__ __launch_bounds__(128) void fc2_kernel(
    const float* __restrict__ fin, const float* __restrict__ w,
    const float* __restrict__ b, float* __restrict__ out) {
  __shared__ float row[128];
  __shared__ float v[10];
  __shared__ float lse;
  int n = blockIdx.x, t = threadIdx.x;
  row[t] = fin[n*128 + t];
  __syncthreads();
  if (t < 10) {
    float s = b[t];
    const float* wr = w + t*128;
    for (int i = 0; i < 128; ++i) s += row[i]*wr[i];
    v[t] = s;
  }
  __syncthreads();
  if (t == 0) {
    float m = v[0];
    for (int i = 1; i < 10; ++i) m = fmaxf(m, v[i]);
    float se = 0.f;
    for (int i = 0; i < 10; ++i) se += expf(v[i] - m);
    lse = m + logf(se);
  }
  __syncthreads();
  if (t < 10) out[n*10 + t] = v[t] - lse;
}

extern "C" void kernel_launch(void* const* d_in, const int* in_sizes, int n_in,
                              void* d_out, int out_size, void* d_ws, size_t ws_size,
                              hipStream_t stream) {
  const float* x     = (const float*)d_in[0];
  const float* depth = (const float*)d_in[1];
  const float* fx    = (const float*)d_in[2];
  const float* c1w0  = (const float*)d_in[3];
  const float* c1w1  = (const float*)d_in[4];
  const float* c1w2  = (const float*)d_in[5];
  const float* c1b   = (const float*)d_in[6];
  const float* c2w0  = (const float*)d_in[7];
  const float* c2w1  = (const float*)d_in[8];
  const float* c2w2  = (const float*)d_in[9];
  const float* c2b   = (const float*)d_in[10];
  const float* fc1w  = (const float*)d_in[11];
  const float* fc1b  = (const float*)d_in[12];
  const float* fc2w  = (const float*)d_in[13];
  const float* fc2b  = (const float*)d_in[14];
  float* out = (float*)d_out;

  char* ws = (char*)d_ws;
  uint32_t* sel  = (uint32_t*)ws;                                        // 3,211,264 B
  float* h1t     = (float*)(ws + 3211264);                               // 51,380,224 B
  float* pooled  = (float*)(ws + 3211264 + 51380224);                    // 12,845,056 B
  float* partial = (float*)(ws + 3211264 + 51380224 + 12845056);         // 1,605,632 B
  float* fc1o    = (float*)(ws + 3211264 + 51380224 + 12845056 + 1605632); // 8,192 B

  sel_kernel<<<3136, 256, 0, stream>>>(depth, fx, sel);
  conv1_kernel<<<3136, 256, 0, stream>>>(x, sel, c1w0, c1w1, c1w2, c1b, h1t);
  conv2_kernel<<<3136, 256, 0, stream>>>(h1t, sel, c2w0, c2w1, c2w2, c2b, pooled);
  fc1_kernel<<<1568, 256, 0, stream>>>(pooled, fc1w, partial);
  fc1_reduce_kernel<<<8, 256, 0, stream>>>(partial, fc1b, fc1o);
  fc2_kernel<<<16, 128, 0, stream>>>(fc1o, fc2w, fc2b, out);
}